// Round 1
// baseline (42598.813 us; speedup 1.0000x reference)
//
#include <hip/hip_runtime.h>
#include <hip/hip_bf16.h>

#define S_LEN 2048
#define BATCH 64
#define HID   512
#define GATES 2048   // 4*HID
#define DIN   512
#define NBLK  32     // recurrent persistent blocks
#define UPB   16     // hidden units per block

typedef __attribute__((ext_vector_type(8))) short short8v;
typedef __attribute__((ext_vector_type(4))) float f32x4;

__device__ inline unsigned short f2bf(float f) {
  union { float f; unsigned u; } a; a.f = f;
  unsigned r = a.u + 0x7fffu + ((a.u >> 16) & 1u);
  return (unsigned short)(r >> 16);
}
__device__ inline float bf2f(unsigned short h) {
  union { unsigned u; float f; } a; a.u = ((unsigned)h) << 16; return a.f;
}

// ---------- kernel 1: split x (fp32) -> bf16 hi + lo ----------
__global__ __launch_bounds__(256) void k_split_x(const float* __restrict__ x,
                                                 unsigned short* __restrict__ xhi,
                                                 unsigned short* __restrict__ xlo) {
  const long total = (long)S_LEN * BATCH * DIN / 4;  // 16777216 float4s
  long i = (long)blockIdx.x * blockDim.x + threadIdx.x;
  const long stride = (long)gridDim.x * blockDim.x;
  for (; i < total; i += stride) {
    float4 v = ((const float4*)x)[i];
    ushort4 hv, lv;
    hv.x = f2bf(v.x); lv.x = f2bf(v.x - bf2f(hv.x));
    hv.y = f2bf(v.y); lv.y = f2bf(v.y - bf2f(hv.y));
    hv.z = f2bf(v.z); lv.z = f2bf(v.z - bf2f(hv.z));
    hv.w = f2bf(v.w); lv.w = f2bf(v.w - bf2f(hv.w));
    ((ushort4*)xhi)[i] = hv;
    ((ushort4*)xlo)[i] = lv;
  }
}

// ---------- kernel 2: weights -> bf16, bias sum ----------
__global__ __launch_bounds__(256) void k_prep_w(const float* __restrict__ Wih,
                                                const float* __restrict__ Whh,
                                                const float* __restrict__ bih,
                                                const float* __restrict__ bhh,
                                                unsigned short* __restrict__ WihB,
                                                unsigned short* __restrict__ WhhB,
                                                float* __restrict__ bias) {
  int i = blockIdx.x * 256 + threadIdx.x;
  if (i < GATES * DIN) {
    WihB[i] = f2bf(Wih[i]);
    WhhB[i] = f2bf(Whh[i]);
  }
  if (i < GATES) bias[i] = bih[i] + bhh[i];
}

// ---------- kernel 3: pre[t][r][b] = sum_k x[t,b,k]*Wih[r,k] + bih[r]+bhh[r] ----------
// M = 2048 (gate rows r), N = 131072 (t*64+b), K = 512. C = A * B^T, both row-major [.,K].
#define BM 128
#define BN 128
#define BK 32
#define LDSROW 40  // padded LDS row stride (elements) to break bank conflicts

__global__ __launch_bounds__(256) void k_gemm_pre(
    const unsigned short* __restrict__ A,   // WihB [2048][512]
    const unsigned short* __restrict__ Bh,  // xhi  [131072][512]
    const unsigned short* __restrict__ Bl,  // xlo
    const float* __restrict__ bias,
    unsigned short* __restrict__ pre)       // [S][2048][64] bf16
{
  __shared__ unsigned short As [BM * LDSROW];
  __shared__ unsigned short Bhs[BM * LDSROW];
  __shared__ unsigned short Bls[BM * LDSROW];

  const int tid  = threadIdx.x;
  const int lane = tid & 63;
  const int wave = tid >> 6;
  const int bm = blockIdx.x & 15;
  const int bn = blockIdx.x >> 4;
  const int wr = wave >> 1, wc = wave & 1;

  f32x4 acc[4][4];
  #pragma unroll
  for (int i = 0; i < 4; ++i)
    #pragma unroll
    for (int j = 0; j < 4; ++j) acc[i][j] = (f32x4){0.f, 0.f, 0.f, 0.f};

  const long arow0 = (long)bm * BM;
  const long brow0 = (long)bn * BN;

  for (int kt = 0; kt < DIN / BK; ++kt) {
    #pragma unroll
    for (int it = 0; it < 2; ++it) {
      int c = tid + it * 256;          // 0..511 chunks of 16B
      int row = c >> 2, kc = c & 3;
      int lbyte = row * (LDSROW * 2) + kc * 16;
      long ga = (arow0 + row) * 512 + kt * BK + kc * 8;
      long gb = (brow0 + row) * 512 + kt * BK + kc * 8;
      *(short8v*)((char*)As  + lbyte) = *(const short8v*)(A  + ga);
      *(short8v*)((char*)Bhs + lbyte) = *(const short8v*)(Bh + gb);
      *(short8v*)((char*)Bls + lbyte) = *(const short8v*)(Bl + gb);
    }
    __syncthreads();

    short8v a[4], bh[4], bl[4];
    #pragma unroll
    for (int mt = 0; mt < 4; ++mt) {
      int r = wr * 64 + mt * 16 + (lane & 15);
      a[mt] = *(const short8v*)((const char*)As + r * (LDSROW * 2) + (lane >> 4) * 16);
    }
    #pragma unroll
    for (int nt = 0; nt < 4; ++nt) {
      int r = wc * 64 + nt * 16 + (lane & 15);
      bh[nt] = *(const short8v*)((const char*)Bhs + r * (LDSROW * 2) + (lane >> 4) * 16);
      bl[nt] = *(const short8v*)((const char*)Bls + r * (LDSROW * 2) + (lane >> 4) * 16);
    }
    #pragma unroll
    for (int mt = 0; mt < 4; ++mt)
      #pragma unroll
      for (int nt = 0; nt < 4; ++nt) {
        acc[mt][nt] = __builtin_amdgcn_mfma_f32_16x16x32_bf16(a[mt], bh[nt], acc[mt][nt], 0, 0, 0);
        acc[mt][nt] = __builtin_amdgcn_mfma_f32_16x16x32_bf16(a[mt], bl[nt], acc[mt][nt], 0, 0, 0);
      }
    __syncthreads();
  }

  #pragma unroll
  for (int mt = 0; mt < 4; ++mt) {
    #pragma unroll
    for (int j = 0; j < 4; ++j) {
      int m = bm * BM + wr * 64 + mt * 16 + (lane >> 4) * 4 + j;
      float bv = bias[m];
      #pragma unroll
      for (int nt = 0; nt < 4; ++nt) {
        int n = bn * BN + wc * 64 + nt * 16 + (lane & 15);
        int t = n >> 6, b = n & 63;
        pre[(long)t * (GATES * BATCH) + (long)m * BATCH + b] = f2bf(acc[mt][nt][j] + bv);
      }
    }
  }
}

// ---------- kernel 4: persistent recurrence ----------
// 32 blocks x 512 threads (8 waves). Block g owns hidden units [g*16, g*16+16).
// W_hh slice held in VGPR B-fragments. h broadcast via global hi/lo bf16 buffers,
// double-buffered, point-to-point monotonic flags (agent scope).
__global__ __launch_bounds__(512, 2) void k_lstm(
    const unsigned short* __restrict__ pre,   // [S][2048][64] bf16
    const unsigned short* __restrict__ WhhB,  // [2048][512] bf16
    unsigned short* __restrict__ hbuf_hi,     // [2][64][512]
    unsigned short* __restrict__ hbuf_lo,
    int* __restrict__ flags,                  // [32]
    float* __restrict__ out)                  // [S*B*H | h_f | c_f]
{
  __shared__ unsigned short lds_hi[BATCH * HID];  // 64KB, XOR-swizzled
  __shared__ unsigned short lds_lo[BATCH * HID];  // 64KB
  __shared__ float gate_lds[BATCH][65];           // pad 65 -> conflict-free-ish

  const int tid  = threadIdx.x;
  const int lane = tid & 63;
  const int wave = tid >> 6;
  const int g    = blockIdx.x;
  const int mi   = wave & 3;   // batch 16-row quad
  const int nih  = wave >> 2;  // gates {nih, nih+2}

  // --- preload W_hh B-fragments (held across all 2048 steps) ---
  short8v bfrag0[16], bfrag1[16];
  {
    int n  = lane & 15;
    int kb = (lane >> 4) * 8;
    long r0 = (long)((nih)     * 512 + g * UPB + n) * 512;
    long r1 = (long)((nih + 2) * 512 + g * UPB + n) * 512;
    #pragma unroll
    for (int ks = 0; ks < 16; ++ks) {
      bfrag0[ks] = *(const short8v*)(WhhB + r0 + ks * 32 + kb);
      bfrag1[ks] = *(const short8v*)(WhhB + r1 + ks * 32 + kb);
    }
  }

  float c0 = 0.f, c1 = 0.f;
  const int b_ew = lane;  // elementwise batch
  const int u_ew = wave;  // elementwise units {wave, wave+8}

  #pragma unroll 1
  for (int t = 0; t < S_LEN; ++t) {
    // prefetch this step's x-gate values (independent of flags -> hides HBM latency)
    unsigned short pv[8];
    {
      const unsigned short* p = pre + (long)t * (GATES * BATCH);
      #pragma unroll
      for (int gate = 0; gate < 4; ++gate) {
        pv[gate * 2 + 0] = p[(gate * 512 + g * UPB + u_ew)     * BATCH + b_ew];
        pv[gate * 2 + 1] = p[(gate * 512 + g * UPB + u_ew + 8) * BATCH + b_ew];
      }
    }

    if (t > 0) {
      // lane-parallel poll of all 32 flags
      while (true) {
        int v = __hip_atomic_load(&flags[lane & 31], __ATOMIC_RELAXED, __HIP_MEMORY_SCOPE_AGENT);
        if (__all(v >= t)) break;
        __builtin_amdgcn_s_sleep(1);
      }
      __threadfence();  // acquire: invalidate stale L1/L2 before reading h
      const unsigned short* shi = hbuf_hi + (t & 1) * (BATCH * HID);
      const unsigned short* slo = hbuf_lo + (t & 1) * (BATCH * HID);
      #pragma unroll
      for (int it = 0; it < 8; ++it) {
        int c = tid + it * 512;          // 0..4095 chunks of 16B per array
        int m = c >> 6, kc = c & 63;
        int byte = (m * 1024 + kc * 16) ^ ((m & 7) << 4);
        *(short8v*)((char*)lds_hi + byte) = *(const short8v*)(shi + m * HID + kc * 8);
        *(short8v*)((char*)lds_lo + byte) = *(const short8v*)(slo + m * HID + kc * 8);
      }
    } else {
      short8v z = (short8v){0, 0, 0, 0, 0, 0, 0, 0};
      #pragma unroll
      for (int it = 0; it < 8; ++it) {
        int c = tid + it * 512;
        *(short8v*)((char*)lds_hi + c * 16) = z;
        *(short8v*)((char*)lds_lo + c * 16) = z;
      }
    }
    __syncthreads();

    // --- recurrent MFMA: gates_h[batch, row] ---
    f32x4 acc0 = (f32x4){0.f, 0.f, 0.f, 0.f};
    f32x4 acc1 = (f32x4){0.f, 0.f, 0.f, 0.f};
    {
      int m    = mi * 16 + (lane & 15);
      int kb2  = (lane >> 4) * 16;
      int base = m * 1024;
      int swz  = (m & 7) << 4;
      #pragma unroll
      for (int ks = 0; ks < 16; ++ks) {
        int byte = (base + ks * 64 + kb2) ^ swz;
        short8v ahi = *(const short8v*)((const char*)lds_hi + byte);
        short8v alo = *(const short8v*)((const char*)lds_lo + byte);
        acc0 = __builtin_amdgcn_mfma_f32_16x16x32_bf16(ahi, bfrag0[ks], acc0, 0, 0, 0);
        acc1 = __builtin_amdgcn_mfma_f32_16x16x32_bf16(ahi, bfrag1[ks], acc1, 0, 0, 0);
        acc0 = __builtin_amdgcn_mfma_f32_16x16x32_bf16(alo, bfrag0[ks], acc0, 0, 0, 0);
        acc1 = __builtin_amdgcn_mfma_f32_16x16x32_bf16(alo, bfrag1[ks], acc1, 0, 0, 0);
      }
    }

    // exchange gates through LDS (i,f,g,o of one unit live in different waves)
    {
      int col0 = nih * 16 + (lane & 15);
      int col1 = (nih + 2) * 16 + (lane & 15);
      int mrow = mi * 16 + (lane >> 4) * 4;
      #pragma unroll
      for (int j = 0; j < 4; ++j) {
        gate_lds[mrow + j][col0] = acc0[j];
        gate_lds[mrow + j][col1] = acc1[j];
      }
    }
    __syncthreads();

    // --- elementwise: thread -> (batch=lane, units {wave, wave+8}) ---
    float hv0, hv1, cv0, cv1;
    {
      int u = u_ew;
      float zi = gate_lds[b_ew][u]      + bf2f(pv[0]);
      float zf = gate_lds[b_ew][16 + u] + bf2f(pv[2]);
      float zg = gate_lds[b_ew][32 + u] + bf2f(pv[4]);
      float zo = gate_lds[b_ew][48 + u] + bf2f(pv[6]);
      float ii = 1.f / (1.f + __expf(-zi));
      float ff = 1.f / (1.f + __expf(-zf));
      float e1 = __expf(2.f * fminf(zg, 15.f));
      float gg = (e1 - 1.f) / (e1 + 1.f);
      float oo = 1.f / (1.f + __expf(-zo));
      float cn = ff * c0 + ii * gg;
      float e2 = __expf(2.f * fminf(cn, 15.f));
      float tc = (e2 - 1.f) / (e2 + 1.f);
      hv0 = oo * tc; cv0 = cn; c0 = cn;
    }
    {
      int u = u_ew + 8;
      float zi = gate_lds[b_ew][u]      + bf2f(pv[1]);
      float zf = gate_lds[b_ew][16 + u] + bf2f(pv[3]);
      float zg = gate_lds[b_ew][32 + u] + bf2f(pv[5]);
      float zo = gate_lds[b_ew][48 + u] + bf2f(pv[7]);
      float ii = 1.f / (1.f + __expf(-zi));
      float ff = 1.f / (1.f + __expf(-zf));
      float e1 = __expf(2.f * fminf(zg, 15.f));
      float gg = (e1 - 1.f) / (e1 + 1.f);
      float oo = 1.f / (1.f + __expf(-zo));
      float cn = ff * c1 + ii * gg;
      float e2 = __expf(2.f * fminf(cn, 15.f));
      float tc = (e2 - 1.f) / (e2 + 1.f);
      hv1 = oo * tc; cv1 = cn; c1 = cn;
    }

    {
      long ob = (long)t * (BATCH * HID) + (long)b_ew * HID + g * UPB;
      out[ob + u_ew]     = hv0;
      out[ob + u_ew + 8] = hv1;
      int hb = ((t + 1) & 1) * (BATCH * HID) + b_ew * HID + g * UPB;
      unsigned short hh0 = f2bf(hv0);
      unsigned short hh1 = f2bf(hv1);
      hbuf_hi[hb + u_ew]     = hh0;
      hbuf_lo[hb + u_ew]     = f2bf(hv0 - bf2f(hh0));
      hbuf_hi[hb + u_ew + 8] = hh1;
      hbuf_lo[hb + u_ew + 8] = f2bf(hv1 - bf2f(hh1));
      if (t == S_LEN - 1) {
        long fb = (long)S_LEN * (BATCH * HID) + (long)b_ew * HID + g * UPB;
        out[fb + u_ew]                  = hv0;
        out[fb + u_ew + 8]              = hv1;
        out[fb + BATCH * HID + u_ew]     = cv0;
        out[fb + BATCH * HID + u_ew + 8] = cv1;
      }
    }

    __threadfence();      // make h slice agent-visible
    __syncthreads();      // all threads' stores ordered before flag
    if (tid == 0) {
      __hip_atomic_store(&flags[g], t + 1, __ATOMIC_RELAXED, __HIP_MEMORY_SCOPE_AGENT);
    }
  }
}

extern "C" void kernel_launch(void* const* d_in, const int* in_sizes, int n_in,
                              void* d_out, int out_size, void* d_ws, size_t ws_size,
                              hipStream_t stream) {
  const float* x   = (const float*)d_in[0];
  const float* Wih = (const float*)d_in[1];
  const float* Whh = (const float*)d_in[2];
  const float* bih = (const float*)d_in[3];
  const float* bhh = (const float*)d_in[4];
  float* out = (float*)d_out;

  char* ws = (char*)d_ws;
  size_t off = 0;
  auto alloc = [&](size_t bytes) -> char* {
    char* p = ws + off;
    off += (bytes + 255) & ~(size_t)255;
    return p;
  };
  unsigned short* xhi  = (unsigned short*)alloc((size_t)S_LEN * BATCH * DIN * 2);      // 128MB
  unsigned short* xlo  = (unsigned short*)alloc((size_t)S_LEN * BATCH * DIN * 2);      // 128MB
  unsigned short* preb = (unsigned short*)alloc((size_t)S_LEN * GATES * BATCH * 2);    // 512MB
  unsigned short* WihB = (unsigned short*)alloc((size_t)GATES * DIN * 2);
  unsigned short* WhhB = (unsigned short*)alloc((size_t)GATES * DIN * 2);
  float*          bias = (float*)alloc((size_t)GATES * 4);
  unsigned short* hbh  = (unsigned short*)alloc((size_t)2 * BATCH * HID * 2);
  unsigned short* hbl  = (unsigned short*)alloc((size_t)2 * BATCH * HID * 2);
  int*            flg  = (int*)alloc(256);

  hipMemsetAsync(flg, 0, 256, stream);  // replay-safe: flags are monotonic within a run
  k_split_x<<<8192, 256, 0, stream>>>(x, xhi, xlo);
  k_prep_w<<<4096, 256, 0, stream>>>(Wih, Whh, bih, bhh, WihB, WhhB, bias);
  k_gemm_pre<<<16384, 256, 0, stream>>>(WihB, xhi, xlo, bias, preb);
  k_lstm<<<NBLK, 512, 0, stream>>>(preb, WhhB, hbh, hbl, flg, out);
}

// Round 2
// 22077.792 us; speedup vs baseline: 1.9295x; 1.9295x over previous
//
#include <hip/hip_runtime.h>
#include <hip/hip_bf16.h>

#define S_LEN 2048
#define BATCH 64
#define HID   512
#define GATES 2048   // 4*HID
#define DIN   512
#define NBLK  32     // recurrent persistent blocks
#define UPB   16     // hidden units per block

typedef __attribute__((ext_vector_type(8))) short short8v;
typedef __attribute__((ext_vector_type(4))) float f32x4;

__device__ inline unsigned short f2bf(float f) {
  union { float f; unsigned u; } a; a.f = f;
  unsigned r = a.u + 0x7fffu + ((a.u >> 16) & 1u);
  return (unsigned short)(r >> 16);
}
__device__ inline float bf2f(unsigned short h) {
  union { unsigned u; float f; } a; a.u = ((unsigned)h) << 16; return a.f;
}

// ---------- kernel 1: split x (fp32) -> bf16 hi + lo ----------
__global__ __launch_bounds__(256) void k_split_x(const float* __restrict__ x,
                                                 unsigned short* __restrict__ xhi,
                                                 unsigned short* __restrict__ xlo) {
  const long total = (long)S_LEN * BATCH * DIN / 4;
  long i = (long)blockIdx.x * blockDim.x + threadIdx.x;
  const long stride = (long)gridDim.x * blockDim.x;
  for (; i < total; i += stride) {
    float4 v = ((const float4*)x)[i];
    ushort4 hv, lv;
    hv.x = f2bf(v.x); lv.x = f2bf(v.x - bf2f(hv.x));
    hv.y = f2bf(v.y); lv.y = f2bf(v.y - bf2f(hv.y));
    hv.z = f2bf(v.z); lv.z = f2bf(v.z - bf2f(hv.z));
    hv.w = f2bf(v.w); lv.w = f2bf(v.w - bf2f(hv.w));
    ((ushort4*)xhi)[i] = hv;
    ((ushort4*)xlo)[i] = lv;
  }
}

// ---------- kernel 2: weights -> bf16, bias sum ----------
__global__ __launch_bounds__(256) void k_prep_w(const float* __restrict__ Wih,
                                                const float* __restrict__ Whh,
                                                const float* __restrict__ bih,
                                                const float* __restrict__ bhh,
                                                unsigned short* __restrict__ WihB,
                                                unsigned short* __restrict__ WhhB,
                                                float* __restrict__ bias) {
  int i = blockIdx.x * 256 + threadIdx.x;
  if (i < GATES * DIN) {
    WihB[i] = f2bf(Wih[i]);
    WhhB[i] = f2bf(Whh[i]);
  }
  if (i < GATES) bias[i] = bih[i] + bhh[i];
}

// ---------- kernel 3: pre[t][r][b] = x[t,b,:]·Wih[r,:] + bih[r]+bhh[r] ----------
#define BM 128
#define BN 128
#define BK 32
#define LDSROW 40

__global__ __launch_bounds__(256) void k_gemm_pre(
    const unsigned short* __restrict__ A,   // WihB [2048][512]
    const unsigned short* __restrict__ Bh,  // xhi  [131072][512]
    const unsigned short* __restrict__ Bl,  // xlo
    const float* __restrict__ bias,
    unsigned short* __restrict__ pre)       // [S][2048][64] bf16
{
  __shared__ unsigned short As [BM * LDSROW];
  __shared__ unsigned short Bhs[BM * LDSROW];
  __shared__ unsigned short Bls[BM * LDSROW];

  const int tid  = threadIdx.x;
  const int lane = tid & 63;
  const int wave = tid >> 6;
  const int bm = blockIdx.x & 15;
  const int bn = blockIdx.x >> 4;
  const int wr = wave >> 1, wc = wave & 1;

  f32x4 acc[4][4];
  #pragma unroll
  for (int i = 0; i < 4; ++i)
    #pragma unroll
    for (int j = 0; j < 4; ++j) acc[i][j] = (f32x4){0.f, 0.f, 0.f, 0.f};

  const long arow0 = (long)bm * BM;
  const long brow0 = (long)bn * BN;

  for (int kt = 0; kt < DIN / BK; ++kt) {
    #pragma unroll
    for (int it = 0; it < 2; ++it) {
      int c = tid + it * 256;
      int row = c >> 2, kc = c & 3;
      int lbyte = row * (LDSROW * 2) + kc * 16;
      long ga = (arow0 + row) * 512 + kt * BK + kc * 8;
      long gb = (brow0 + row) * 512 + kt * BK + kc * 8;
      *(short8v*)((char*)As  + lbyte) = *(const short8v*)(A  + ga);
      *(short8v*)((char*)Bhs + lbyte) = *(const short8v*)(Bh + gb);
      *(short8v*)((char*)Bls + lbyte) = *(const short8v*)(Bl + gb);
    }
    __syncthreads();

    short8v a[4], bh[4], bl[4];
    #pragma unroll
    for (int mt = 0; mt < 4; ++mt) {
      int r = wr * 64 + mt * 16 + (lane & 15);
      a[mt] = *(const short8v*)((const char*)As + r * (LDSROW * 2) + (lane >> 4) * 16);
    }
    #pragma unroll
    for (int nt = 0; nt < 4; ++nt) {
      int r = wc * 64 + nt * 16 + (lane & 15);
      bh[nt] = *(const short8v*)((const char*)Bhs + r * (LDSROW * 2) + (lane >> 4) * 16);
      bl[nt] = *(const short8v*)((const char*)Bls + r * (LDSROW * 2) + (lane >> 4) * 16);
    }
    #pragma unroll
    for (int mt = 0; mt < 4; ++mt)
      #pragma unroll
      for (int nt = 0; nt < 4; ++nt) {
        acc[mt][nt] = __builtin_amdgcn_mfma_f32_16x16x32_bf16(a[mt], bh[nt], acc[mt][nt], 0, 0, 0);
        acc[mt][nt] = __builtin_amdgcn_mfma_f32_16x16x32_bf16(a[mt], bl[nt], acc[mt][nt], 0, 0, 0);
      }
    __syncthreads();
  }

  #pragma unroll
  for (int mt = 0; mt < 4; ++mt) {
    #pragma unroll
    for (int j = 0; j < 4; ++j) {
      int m = bm * BM + wr * 64 + mt * 16 + (lane >> 4) * 4 + j;
      float bv = bias[m];
      #pragma unroll
      for (int nt = 0; nt < 4; ++nt) {
        int n = bn * BN + wc * 64 + nt * 16 + (lane & 15);
        int t = n >> 6, b = n & 63;
        pre[(long)t * (GATES * BATCH) + (long)m * BATCH + b] = f2bf(acc[mt][nt][j] + bv);
      }
    }
  }
}

// ---------- kernel 4: persistent recurrence, fence-free MALL-coherent sync ----------
// 32 blocks x 512 threads. Block g owns hidden units [g*16, g*16+16).
// h broadcast via bf16 hbuf with relaxed agent-scope (sc1, cache-bypassing)
// atomics: writer drains vmcnt(0) (the __syncthreads) BEFORE issuing the flag
// store, so h is at the MALL coherence point before the flag can be observed;
// reader sc1 loads issued after the poll therefore see it. No threadfence,
// no L2 writeback/invalidate anywhere in the loop.
__global__ __launch_bounds__(512, 2) void k_lstm(
    const unsigned short* __restrict__ pre,   // [S][2048][64] bf16
    const unsigned short* __restrict__ WhhB,  // [2048][512] bf16
    unsigned short* __restrict__ hbuf,        // [2][64][512] bf16
    int* __restrict__ flags,                  // [32] stride 16 ints (64 B)
    float* __restrict__ out)                  // [S*B*H | h_f | c_f]
{
  __shared__ float gate_lds[BATCH][65];

  const int tid  = threadIdx.x;
  const int lane = tid & 63;
  const int wave = tid >> 6;
  const int g    = blockIdx.x;
  const int mi   = wave & 3;   // batch 16-row quad for MFMA A
  const int nih  = wave >> 2;  // this wave computes gates {nih, nih+2}

  // --- preload W_hh B-fragments (held in VGPRs across all 2048 steps) ---
  short8v bfrag0[16], bfrag1[16];
  {
    int n  = lane & 15;
    int kb = (lane >> 4) * 8;
    long r0 = (long)((nih)     * 512 + g * UPB + n) * 512;
    long r1 = (long)((nih + 2) * 512 + g * UPB + n) * 512;
    #pragma unroll
    for (int ks = 0; ks < 16; ++ks) {
      bfrag0[ks] = *(const short8v*)(WhhB + r0 + ks * 32 + kb);
      bfrag1[ks] = *(const short8v*)(WhhB + r1 + ks * 32 + kb);
    }
  }

  float c0 = 0.f, c1 = 0.f;
  const int b_ew = lane;            // elementwise batch row
  const int u0 = wave * 2;          // elementwise units: adjacent pair
  const int u1 = wave * 2 + 1;

  const int arow = mi * 16 + (lane & 15);   // A-fragment batch row
  const int akk  = (lane >> 4) * 8;         // A-fragment k sub-offset

  #pragma unroll 1
  for (int t = 0; t < S_LEN; ++t) {
    // prefetch this step's x-gate values (plain cached loads, issued BEFORE
    // the poll so ~900cy HBM latency hides under the wait)
    unsigned short pv[8];
    {
      const unsigned short* p = pre + (long)t * (GATES * BATCH);
      #pragma unroll
      for (int gate = 0; gate < 4; ++gate) {
        pv[gate * 2 + 0] = p[(gate * 512 + g * UPB + u0) * BATCH + b_ew];
        pv[gate * 2 + 1] = p[(gate * 512 + g * UPB + u1) * BATCH + b_ew];
      }
    }

    f32x4 acc0 = (f32x4){0.f, 0.f, 0.f, 0.f};
    f32x4 acc1 = (f32x4){0.f, 0.f, 0.f, 0.f};

    if (t > 0) {
      // lane-parallel poll; skip own block's flag (barrier already proved it)
      const int fi = lane & 31;
      const bool own = (fi == g);
      while (true) {
        int v = own ? 0x7fffffff
                    : __hip_atomic_load(&flags[fi * 16], __ATOMIC_RELAXED,
                                        __HIP_MEMORY_SCOPE_AGENT);
        if (__all(v >= t)) break;
        __builtin_amdgcn_s_sleep(1);
      }
      asm volatile("" ::: "memory");  // compiler fence: keep h loads below poll

      // A-fragments straight from global (MALL) into VGPRs — no LDS staging
      const unsigned long long* hb =
          (const unsigned long long*)(hbuf + (t & 1) * (BATCH * HID));
      unsigned long long av[32];
      #pragma unroll
      for (int ks = 0; ks < 16; ++ks) {
        long e = ((long)arow * 512 + ks * 32 + akk) >> 2;  // u64 index
        av[ks * 2 + 0] = __hip_atomic_load(hb + e,     __ATOMIC_RELAXED,
                                           __HIP_MEMORY_SCOPE_AGENT);
        av[ks * 2 + 1] = __hip_atomic_load(hb + e + 1, __ATOMIC_RELAXED,
                                           __HIP_MEMORY_SCOPE_AGENT);
      }
      #pragma unroll
      for (int ks = 0; ks < 16; ++ks) {
        union { unsigned long long q[2]; short8v v; } u;
        u.q[0] = av[ks * 2]; u.q[1] = av[ks * 2 + 1];
        acc0 = __builtin_amdgcn_mfma_f32_16x16x32_bf16(u.v, bfrag0[ks], acc0, 0, 0, 0);
        acc1 = __builtin_amdgcn_mfma_f32_16x16x32_bf16(u.v, bfrag1[ks], acc1, 0, 0, 0);
      }
    }

    // exchange gate partials through LDS (i,f,g,o of a unit live in 2 waves)
    {
      int n    = lane & 15;
      int col0 = nih * 16 + n;
      int col1 = (nih + 2) * 16 + n;
      int mrow = mi * 16 + (lane >> 4) * 4;
      #pragma unroll
      for (int j = 0; j < 4; ++j) {
        gate_lds[mrow + j][col0] = acc0[j];
        gate_lds[mrow + j][col1] = acc1[j];
      }
    }
    __syncthreads();

    // --- elementwise: thread -> (batch=lane, units {u0, u1}) ---
    float hv0, hv1, cv0, cv1;
    {
      float zi = gate_lds[b_ew][u0]      + bf2f(pv[0]);
      float zf = gate_lds[b_ew][16 + u0] + bf2f(pv[2]);
      float zg = gate_lds[b_ew][32 + u0] + bf2f(pv[4]);
      float zo = gate_lds[b_ew][48 + u0] + bf2f(pv[6]);
      float ii = 1.f / (1.f + __expf(-zi));
      float ff = 1.f / (1.f + __expf(-zf));
      float e1 = __expf(2.f * fminf(zg, 15.f));
      float gg = (e1 - 1.f) / (e1 + 1.f);
      float oo = 1.f / (1.f + __expf(-zo));
      float cn = ff * c0 + ii * gg;
      float e2 = __expf(2.f * fminf(cn, 15.f));
      float tc = (e2 - 1.f) / (e2 + 1.f);
      hv0 = oo * tc; cv0 = cn; c0 = cn;
    }
    {
      float zi = gate_lds[b_ew][u1]      + bf2f(pv[1]);
      float zf = gate_lds[b_ew][16 + u1] + bf2f(pv[3]);
      float zg = gate_lds[b_ew][32 + u1] + bf2f(pv[5]);
      float zo = gate_lds[b_ew][48 + u1] + bf2f(pv[7]);
      float ii = 1.f / (1.f + __expf(-zi));
      float ff = 1.f / (1.f + __expf(-zf));
      float e1 = __expf(2.f * fminf(zg, 15.f));
      float gg = (e1 - 1.f) / (e1 + 1.f);
      float oo = 1.f / (1.f + __expf(-zo));
      float cn = ff * c1 + ii * gg;
      float e2 = __expf(2.f * fminf(cn, 15.f));
      float tc = (e2 - 1.f) / (e2 + 1.f);
      hv1 = oo * tc; cv1 = cn; c1 = cn;
    }

    // --- stores: out (plain, contiguous float2) + h broadcast (sc1 atomic) ---
    {
      long ob = (long)t * (BATCH * HID) + (long)b_ew * HID + g * UPB + u0;
      float2 o2; o2.x = hv0; o2.y = hv1;
      *(float2*)(out + ob) = o2;

      unsigned pack = (unsigned)f2bf(hv0) | ((unsigned)f2bf(hv1) << 16);
      unsigned* hw = (unsigned*)(hbuf + ((t + 1) & 1) * (BATCH * HID)
                                 + b_ew * HID + g * UPB + u0);
      __hip_atomic_store(hw, pack, __ATOMIC_RELAXED, __HIP_MEMORY_SCOPE_AGENT);

      if (t == S_LEN - 1) {
        long fb = (long)S_LEN * (BATCH * HID) + (long)b_ew * HID + g * UPB + u0;
        float2 h2; h2.x = hv0; h2.y = hv1;
        float2 c2; c2.x = cv0; c2.y = cv1;
        *(float2*)(out + fb) = h2;
        *(float2*)(out + fb + BATCH * HID) = c2;
      }
    }

    // release: drain ALL threads' vmcnt (h stores reach the MALL coherence
    // point), then publish the flag. No L2 writeback needed: the h stores
    // were write-through (sc1) and never dirty in L2.
    asm volatile("s_waitcnt vmcnt(0)" ::: "memory");
    __syncthreads();
    if (tid == 0) {
      __hip_atomic_store(&flags[g * 16], t + 1, __ATOMIC_RELAXED,
                         __HIP_MEMORY_SCOPE_AGENT);
    }
  }
}

extern "C" void kernel_launch(void* const* d_in, const int* in_sizes, int n_in,
                              void* d_out, int out_size, void* d_ws, size_t ws_size,
                              hipStream_t stream) {
  const float* x   = (const float*)d_in[0];
  const float* Wih = (const float*)d_in[1];
  const float* Whh = (const float*)d_in[2];
  const float* bih = (const float*)d_in[3];
  const float* bhh = (const float*)d_in[4];
  float* out = (float*)d_out;

  char* ws = (char*)d_ws;
  size_t off = 0;
  auto alloc = [&](size_t bytes) -> char* {
    char* p = ws + off;
    off += (bytes + 255) & ~(size_t)255;
    return p;
  };
  unsigned short* xhi  = (unsigned short*)alloc((size_t)S_LEN * BATCH * DIN * 2);
  unsigned short* xlo  = (unsigned short*)alloc((size_t)S_LEN * BATCH * DIN * 2);
  unsigned short* preb = (unsigned short*)alloc((size_t)S_LEN * GATES * BATCH * 2);
  unsigned short* WihB = (unsigned short*)alloc((size_t)GATES * DIN * 2);
  unsigned short* WhhB = (unsigned short*)alloc((size_t)GATES * DIN * 2);
  float*          bias = (float*)alloc((size_t)GATES * 4);
  unsigned short* hbuf = (unsigned short*)alloc((size_t)2 * BATCH * HID * 2);
  int*            flg  = (int*)alloc(32 * 16 * sizeof(int));

  hipMemsetAsync(flg, 0, 32 * 16 * sizeof(int), stream);  // replay-safe
  k_split_x<<<8192, 256, 0, stream>>>(x, xhi, xlo);
  k_prep_w<<<4096, 256, 0, stream>>>(Wih, Whh, bih, bhh, WihB, WhhB, bias);
  k_gemm_pre<<<16384, 256, 0, stream>>>(WihB, xhi, xlo, bias, preb);
  k_lstm<<<NBLK, 512, 0, stream>>>(preb, WhhB, hbuf, flg, out);
}